// Round 8
// baseline (15935.986 us; speedup 1.0000x reference)
//
#include <hip/hip_runtime.h>
#include <math.h>

// TD3ActorDSNN — f32 class-faithful, fused, round 8.
// Exactness invariants (validated r4-r6):
//  - per-element k-ascending single-accumulator f32 chains for h0 and h1;
//    skipping zero terms is bit-identical; add order never changes.
//  - recurrences: __fadd_rn(__fmul_rn(beta,state),h) (np mul-then-add).
//  - layer2/mem2: order-free (tanh input, tol 2e-2 >> 1e-6 noise).
// Round-8 insight: mem0 starts at 0.0f and resets to exactly 0.0f, so with
// constant h the spike pattern is EXACTLY periodic: mask = bits at
// t = n-1, 2n-1, ... where n = ctz(mask)+1. Only 16 mask values exist.
// h1 inner loop: wave-uniform switch(ctz) -> pure v_add bodies with
// compile-time acc indices. No bit-builds, no fmacs, no inline asm
// (round-7's asm caused scratch spills: WRITE_SIZE 16MB -> 9GB).

typedef unsigned int u32;
typedef unsigned short u16;

// ---- K1: h0 = inputs @ W0 (f32 fma chain) + fused mem0 recurrence -> s0bR ----
__global__ __launch_bounds__(256) void h0_kernel(
    const float* __restrict__ in, const float* __restrict__ W0,
    u16* __restrict__ s0bR) {
    __shared__ float Ls[32 * 512];
    int tid = threadIdx.x;
    int j = blockIdx.x * 256 + tid;
    int r0 = blockIdx.y * 32;
#pragma unroll
    for (int i = 0; i < 64; ++i) {
        int e = i * 256 + tid;
        Ls[e] = in[(size_t)(r0 + (e >> 9)) * 512 + (e & 511)];
    }
    __syncthreads();
    float acc[32];
#pragma unroll
    for (int r = 0; r < 32; ++r) acc[r] = 0.f;
    for (int k = 0; k < 512; ++k) {
        float w = W0[(size_t)k * 2048 + j];
#pragma unroll
        for (int r = 0; r < 32; ++r)
            acc[r] = __fmaf_rn(Ls[r * 512 + k], w, acc[r]);
    }
#pragma unroll
    for (int r = 0; r < 32; ++r) {
        float h = acc[r], mem = 0.f;
        u32 bits = 0;
#pragma unroll
        for (int t = 0; t < 15; ++t) {
            float nm = __fadd_rn(__fmul_rn(0.85f, mem), h);  // np: mul, then add
            bool sp = nm > 1.0f;
            bits |= (sp ? 1u : 0u) << t;
            mem = sp ? 0.f : nm;
        }
        s0bR[(size_t)(r0 + r) * 2048 + j] = (u16)bits;
    }
}

// ---- K2: FUSED h1 (15 steps) + in-register syn1/mem1 recurrence -> s1b ----
// Wave: 1 row x 256 cols (lane: 4 cols via float4). Block: 4 rows.
// grid 8192: jb = id&7 (XCD-affine W1 slice), rblk = id>>3.
#define ACC_ADD(T)                                   \
    acc[T][0] = __fadd_rn(acc[T][0], w.x);           \
    acc[T][1] = __fadd_rn(acc[T][1], w.y);           \
    acc[T][2] = __fadd_rn(acc[T][2], w.z);           \
    acc[T][3] = __fadd_rn(acc[T][3], w.w)

__global__ __launch_bounds__(256, 4) void h1_fused4(
    const float* __restrict__ W1, const u16* __restrict__ s0bR,
    u16* __restrict__ s1b) {
    int id = blockIdx.x;
    int jb = id & 7, rblk = id >> 3;
    int lane = threadIdx.x & 63, wv = threadIdx.x >> 6;
    int row = rblk * 4 + wv;
    int j0 = jb * 256 + lane * 4;
    const float* wp = W1 + j0;
    const u16* mp = s0bR + (size_t)row * 2048;

    float acc[15][4];
#pragma unroll
    for (int t = 0; t < 15; ++t)
#pragma unroll
        for (int q = 0; q < 4; ++q) acc[t][q] = 0.f;

    uint4 m8 = *(const uint4*)(mp);         // masks k=0..7
    for (int kb = 0; kb < 2048; kb += 8) {
        // lookahead (last group overruns into s1b region; values unused)
        uint4 m8n = *(const uint4*)(mp + kb + 8);
#pragma unroll
        for (int kk = 0; kk < 8; ++kk) {
            u32 word = (kk < 2) ? m8.x : (kk < 4) ? m8.y : (kk < 6) ? m8.z : m8.w;
            u32 mask = __builtin_amdgcn_readfirstlane(
                           (kk & 1) ? (word >> 16) : word) & 0x7FFFu;
            if (mask) {                      // wave-uniform (~44% taken)
                float4 w = *(const float4*)(wp + (size_t)(kb + kk) * 2048);
                // periodic pattern: spikes at t = n-1, 2n-1, ...; n = ctz+1
                switch (__builtin_ctz(mask)) {
                case 0:  ACC_ADD(0); ACC_ADD(1); ACC_ADD(2); ACC_ADD(3);
                         ACC_ADD(4); ACC_ADD(5); ACC_ADD(6); ACC_ADD(7);
                         ACC_ADD(8); ACC_ADD(9); ACC_ADD(10); ACC_ADD(11);
                         ACC_ADD(12); ACC_ADD(13); ACC_ADD(14); break;
                case 1:  ACC_ADD(1); ACC_ADD(3); ACC_ADD(5); ACC_ADD(7);
                         ACC_ADD(9); ACC_ADD(11); ACC_ADD(13); break;
                case 2:  ACC_ADD(2); ACC_ADD(5); ACC_ADD(8); ACC_ADD(11);
                         ACC_ADD(14); break;
                case 3:  ACC_ADD(3); ACC_ADD(7); ACC_ADD(11); break;
                case 4:  ACC_ADD(4); ACC_ADD(9); ACC_ADD(14); break;
                case 5:  ACC_ADD(5); ACC_ADD(11); break;
                case 6:  ACC_ADD(6); ACC_ADD(13); break;
                case 7:  ACC_ADD(7); break;
                case 8:  ACC_ADD(8); break;
                case 9:  ACC_ADD(9); break;
                case 10: ACC_ADD(10); break;
                case 11: ACC_ADD(11); break;
                case 12: ACC_ADD(12); break;
                case 13: ACC_ADD(13); break;
                case 14: ACC_ADD(14); break;
                }
            }
        }
        m8 = m8n;
    }

    // layer-1 recurrence per element (np rounding order) -> s1 bitmasks
    u16 ob[4];
#pragma unroll
    for (int q = 0; q < 4; ++q) {
        float syn = 0.f, mem = 0.f;
        u32 obits = 0;
#pragma unroll
        for (int t = 0; t < 15; ++t) {
            float ns = __fadd_rn(__fmul_rn(0.9f, syn), acc[t][q]);
            float nm = __fadd_rn(__fmul_rn(0.85f, mem), ns);
            bool sp = nm > 1.0f;
            obits |= (sp ? 1u : 0u) << t;
            syn = ns;
            mem = sp ? 0.f : nm;
        }
        ob[q] = (u16)obits;
    }
    uint2 pk;
    pk.x = (u32)ob[0] | ((u32)ob[1] << 16);
    pk.y = (u32)ob[2] | ((u32)ob[3] << 16);
    *(uint2*)(s1b + (size_t)row * 2048 + j0) = pk;
}

// ---- K3: out = tanh(sum_t s1_t @ W2) (order-free reduction) ----
__global__ __launch_bounds__(256) void out_kernel(
    const u16* __restrict__ s1b, const float* __restrict__ W2,
    float* __restrict__ out) {
    __shared__ float P[4][15][8];
    int row = blockIdx.x;
    int tid = threadIdx.x, lane = tid & 63, wv = tid >> 6;
    const u16* srow = s1b + (size_t)row * 2048;
    union { uint4 v; u16 m[8]; } u;
    u.v = *(const uint4*)(srow + tid * 8);
#pragma unroll
    for (int t = 0; t < 15; ++t) {
        float a[8];
#pragma unroll
        for (int jj = 0; jj < 8; ++jj) a[jj] = 0.f;
#pragma unroll
        for (int kk = 0; kk < 8; ++kk) {
            const float* wr = W2 + (size_t)(tid * 8 + kk) * 8;
            if ((u.m[kk] >> t) & 1u) {
#pragma unroll
                for (int jj = 0; jj < 8; ++jj)
                    a[jj] = __fadd_rn(a[jj], wr[jj]);
            }
        }
#pragma unroll
        for (int jj = 0; jj < 8; ++jj) {
            float v = a[jj];
#pragma unroll
            for (int m = 1; m < 64; m <<= 1) v += __shfl_xor(v, m, 64);
            a[jj] = v;
        }
        if (lane == 0) {
#pragma unroll
            for (int jj = 0; jj < 8; ++jj) P[wv][t][jj] = a[jj];
        }
    }
    __syncthreads();
    if (tid < 8) {
        float m2 = 0.f;
#pragma unroll
        for (int t = 0; t < 15; ++t) {
            float s = __fadd_rn(__fadd_rn(P[0][t][tid], P[1][t][tid]),
                                __fadd_rn(P[2][t][tid], P[3][t][tid]));
            m2 = __fadd_rn(m2, s);
        }
        out[(size_t)row * 8 + tid] = tanhf(m2);
    }
}

extern "C" void kernel_launch(void* const* d_in, const int* in_sizes, int n_in,
                              void* d_out, int out_size, void* d_ws, size_t ws_size,
                              hipStream_t stream) {
    const float* inp = (const float*)d_in[0];
    const float* W0  = (const float*)d_in[1];
    const float* W1  = (const float*)d_in[2];
    const float* W2  = (const float*)d_in[3];
    float* out = (float*)d_out;
    char* ws = (char*)d_ws;

    u16* s0bR = (u16*)(ws + 0);           // 16,777,216  [row][k] 15-bit masks
    u16* s1b  = (u16*)(ws + 16777216);    // 16,777,216  [row][j] 15-bit masks
    if (ws_size < 33554432) return;       // 32 MB scratch

    h0_kernel<<<dim3(8, 128), 256, 0, stream>>>(inp, W0, s0bR);
    h1_fused4<<<8192, 256, 0, stream>>>(W1, s0bR, s1b);
    out_kernel<<<4096, 256, 0, stream>>>(s1b, W2, out);
}

// Round 9
// 3470.391 us; speedup vs baseline: 4.5920x; 4.5920x over previous
//
#include <hip/hip_runtime.h>
#include <math.h>

// TD3ActorDSNN — f32 class-faithful, fused, round 9.
// Exactness invariants (validated r4-r6):
//  - per-element k-ascending single-accumulator f32 chains for h0 and h1;
//    skipping zero terms is bit-identical; add order never changes.
//  - b in {0,1}: b*w is EXACT (0 or w), so mul+add == fma == conditional add,
//    all bit-identical. v_pk_fma_f32 = two independent IEEE fmas -> exact.
//  - recurrences: __fadd_rn(__fmul_rn(beta,state),h) (np mul-then-add).
//  - layer2/mem2: order-free (tanh input, tol 2e-2 >> 1e-6 noise).
// Round 7/8 lesson: multi-way branches (or asm operands) inside the k-loop
// touching the 60 live accumulators => allocator spills to scratch
// (WRITE_SIZE 16MB -> 10GB, 2-4x regression). Round 9 keeps round-6's
// straight-line body + single if(mask) guard; changes ONLY the arithmetic:
//  - mask via readfirstlane -> SGPR; b = scalar select (s_bitcmp+s_cselect,
//    SALU pipe, 0 VALU) instead of v_bfe+v_cvt (2 VALU).
//  - float2 accumulators -> v_pk_fma_f32 (2 VALU per t instead of 4).

typedef unsigned int u32;
typedef unsigned short u16;
typedef __attribute__((ext_vector_type(2))) float f32x2;

// ---- K1: h0 = inputs @ W0 (f32 fma chain) + fused mem0 recurrence -> s0bR ----
__global__ __launch_bounds__(256) void h0_kernel(
    const float* __restrict__ in, const float* __restrict__ W0,
    u16* __restrict__ s0bR) {
    __shared__ float Ls[32 * 512];
    int tid = threadIdx.x;
    int j = blockIdx.x * 256 + tid;
    int r0 = blockIdx.y * 32;
#pragma unroll
    for (int i = 0; i < 64; ++i) {
        int e = i * 256 + tid;
        Ls[e] = in[(size_t)(r0 + (e >> 9)) * 512 + (e & 511)];
    }
    __syncthreads();
    float acc[32];
#pragma unroll
    for (int r = 0; r < 32; ++r) acc[r] = 0.f;
    for (int k = 0; k < 512; ++k) {
        float w = W0[(size_t)k * 2048 + j];
#pragma unroll
        for (int r = 0; r < 32; ++r)
            acc[r] = __fmaf_rn(Ls[r * 512 + k], w, acc[r]);
    }
#pragma unroll
    for (int r = 0; r < 32; ++r) {
        float h = acc[r], mem = 0.f;
        u32 bits = 0;
#pragma unroll
        for (int t = 0; t < 15; ++t) {
            float nm = __fadd_rn(__fmul_rn(0.85f, mem), h);  // np: mul, then add
            bool sp = nm > 1.0f;
            bits |= (sp ? 1u : 0u) << t;
            mem = sp ? 0.f : nm;
        }
        s0bR[(size_t)(r0 + r) * 2048 + j] = (u16)bits;
    }
}

// ---- K2: FUSED h1 (15 steps) + in-register syn1/mem1 recurrence -> s1b ----
// Wave: 1 row x 256 cols (lane: 4 cols via float4 -> 2x f32x2). Block: 4 rows.
// grid 8192: jb = id&7 (XCD-affine W1 slice), rblk = id>>3.
__global__ __launch_bounds__(256, 4) void h1_fused5(
    const float* __restrict__ W1, const u16* __restrict__ s0bR,
    u16* __restrict__ s1b) {
    int id = blockIdx.x;
    int jb = id & 7, rblk = id >> 3;
    int lane = threadIdx.x & 63, wv = threadIdx.x >> 6;
    int row = rblk * 4 + wv;
    int j0 = jb * 256 + lane * 4;
    const float* wp = W1 + j0;
    const u16* mp = s0bR + (size_t)row * 2048;

    f32x2 acc[15][2];
#pragma unroll
    for (int t = 0; t < 15; ++t) {
        acc[t][0] = (f32x2){0.f, 0.f};
        acc[t][1] = (f32x2){0.f, 0.f};
    }

    float4 wc = *(const float4*)(wp);       // w for k=0
    uint4 m8 = *(const uint4*)(mp);         // masks k=0..7
    for (int kb = 0; kb < 2048; kb += 8) {
        // lookahead (last group overruns into s1b region; values unused)
        uint4 m8n = *(const uint4*)(mp + kb + 8);
#pragma unroll
        for (int kk = 0; kk < 8; ++kk) {
            int k = kb + kk;
            float4 wcur = wc;
            // prefetch next k's w (guard last k; uniform select)
            wc = *(const float4*)(wp + (size_t)(k < 2047 ? k + 1 : k) * 2048);
            u32 word = (kk < 2) ? m8.x : (kk < 4) ? m8.y : (kk < 6) ? m8.z : m8.w;
            u32 mask = __builtin_amdgcn_readfirstlane(
                           (kk & 1) ? (word >> 16) : word) & 0x7FFFu;
            if (mask) {                      // single uniform guard (~44% taken)
                f32x2 w01 = {wcur.x, wcur.y};
                f32x2 w23 = {wcur.z, wcur.w};
#pragma unroll
                for (int t = 0; t < 15; ++t) {
                    // scalar bit-test -> SGPR float b (s_bitcmp + s_cselect)
                    float b = (mask & (1u << t)) ? 1.0f : 0.0f;
                    f32x2 b2 = {b, b};
                    // b*w exact (b in {0,1}) -> pk_fma bit-identical to cond add
                    acc[t][0] = b2 * w01 + acc[t][0];
                    acc[t][1] = b2 * w23 + acc[t][1];
                }
            }
        }
        m8 = m8n;
    }

    // layer-1 recurrence per element (np rounding order) -> s1 bitmasks
    u16 ob[4];
#pragma unroll
    for (int q = 0; q < 4; ++q) {
        float syn = 0.f, mem = 0.f;
        u32 obits = 0;
#pragma unroll
        for (int t = 0; t < 15; ++t) {
            float h1 = acc[t][q >> 1][q & 1];   // static indices after unroll
            float ns = __fadd_rn(__fmul_rn(0.9f, syn), h1);
            float nm = __fadd_rn(__fmul_rn(0.85f, mem), ns);
            bool sp = nm > 1.0f;
            obits |= (sp ? 1u : 0u) << t;
            syn = ns;
            mem = sp ? 0.f : nm;
        }
        ob[q] = (u16)obits;
    }
    uint2 pk;
    pk.x = (u32)ob[0] | ((u32)ob[1] << 16);
    pk.y = (u32)ob[2] | ((u32)ob[3] << 16);
    *(uint2*)(s1b + (size_t)row * 2048 + j0) = pk;
}

// ---- K3: out = tanh(sum_t s1_t @ W2) (order-free reduction) ----
__global__ __launch_bounds__(256) void out_kernel(
    const u16* __restrict__ s1b, const float* __restrict__ W2,
    float* __restrict__ out) {
    __shared__ float P[4][15][8];
    int row = blockIdx.x;
    int tid = threadIdx.x, lane = tid & 63, wv = tid >> 6;
    const u16* srow = s1b + (size_t)row * 2048;
    union { uint4 v; u16 m[8]; } u;
    u.v = *(const uint4*)(srow + tid * 8);
#pragma unroll
    for (int t = 0; t < 15; ++t) {
        float a[8];
#pragma unroll
        for (int jj = 0; jj < 8; ++jj) a[jj] = 0.f;
#pragma unroll
        for (int kk = 0; kk < 8; ++kk) {
            const float* wr = W2 + (size_t)(tid * 8 + kk) * 8;
            if ((u.m[kk] >> t) & 1u) {
#pragma unroll
                for (int jj = 0; jj < 8; ++jj)
                    a[jj] = __fadd_rn(a[jj], wr[jj]);
            }
        }
#pragma unroll
        for (int jj = 0; jj < 8; ++jj) {
            float v = a[jj];
#pragma unroll
            for (int m = 1; m < 64; m <<= 1) v += __shfl_xor(v, m, 64);
            a[jj] = v;
        }
        if (lane == 0) {
#pragma unroll
            for (int jj = 0; jj < 8; ++jj) P[wv][t][jj] = a[jj];
        }
    }
    __syncthreads();
    if (tid < 8) {
        float m2 = 0.f;
#pragma unroll
        for (int t = 0; t < 15; ++t) {
            float s = __fadd_rn(__fadd_rn(P[0][t][tid], P[1][t][tid]),
                                __fadd_rn(P[2][t][tid], P[3][t][tid]));
            m2 = __fadd_rn(m2, s);
        }
        out[(size_t)row * 8 + tid] = tanhf(m2);
    }
}

extern "C" void kernel_launch(void* const* d_in, const int* in_sizes, int n_in,
                              void* d_out, int out_size, void* d_ws, size_t ws_size,
                              hipStream_t stream) {
    const float* inp = (const float*)d_in[0];
    const float* W0  = (const float*)d_in[1];
    const float* W1  = (const float*)d_in[2];
    const float* W2  = (const float*)d_in[3];
    float* out = (float*)d_out;
    char* ws = (char*)d_ws;

    u16* s0bR = (u16*)(ws + 0);           // 16,777,216  [row][k] 15-bit masks
    u16* s1b  = (u16*)(ws + 16777216);    // 16,777,216  [row][j] 15-bit masks
    if (ws_size < 33554432) return;       // 32 MB scratch

    h0_kernel<<<dim3(8, 128), 256, 0, stream>>>(inp, W0, s0bR);
    h1_fused5<<<8192, 256, 0, stream>>>(W1, s0bR, s1b);
    out_kernel<<<4096, 256, 0, stream>>>(s1b, W2, out);
}